// Round 3
// baseline (182.519 us; speedup 1.0000x reference)
//
#include <hip/hip_runtime.h>
#include <hip/hip_bf16.h>

// Problem constants (M=41 in the reference)
#define M41    41
#define HALF   20
#define NPAIR  1261            // #(m,n) with |m|,|n|<=20 and |m+n|<=20
#define NTRIP  (NPAIR * M41)   // 51701 triplets per plane
#define QSLOTS 28              // max distinct q per 1024-t block window (<=26) + slack

// R9 DIAGNOSTIC: REP=8 (R8 was REP=2; marginal pass cost measured at 9.3 us).
// Same idempotent-rewrite trick; the 8x dispatch (~75-115 us) must clear the
// ~67 us harness-fill cutoff so the kernel's own rocprof row finally appears.
// KEEP BODY IDENTICAL TO R8 FOR CLEAN ATTRIBUTION. Revert REP to 1 after reading.
#define REP 8

#if defined(__has_builtin)
# if __has_builtin(__builtin_amdgcn_cvt_pk_bf16_f32)
#  define HAVE_PK_BF16 1
# endif
#endif

static __device__ __forceinline__ unsigned short f2bf_sw(float f) {
    unsigned int u = __float_as_uint(f);
    unsigned int r = u + 0x7fffu + ((u >> 16) & 1u);   // RNE (finite inputs)
    return (unsigned short)(r >> 16);
}
static __device__ __forceinline__ unsigned int pk2(float lo, float hi) {
#ifdef HAVE_PK_BF16
    typedef __bf16 bf2 __attribute__((ext_vector_type(2)));
    union { bf2 v; unsigned int u; } cv;
    cv.v = __builtin_amdgcn_cvt_pk_bf16_f32(lo, hi);   // lo -> low half
    return cv.u;
#else
    return (unsigned int)f2bf_sw(lo) | ((unsigned int)f2bf_sw(hi) << 16);
#endif
}

// q -> packed (mi | ni<<8 | mni<<16).  Closed-form inversion of the Python
// (m,n) enumeration; integer while-loops make it exact for all q.
static __device__ __forceinline__ int pair_decode(int q) {
    int qq = q; bool flip = false;
    if (qq >= 651) { qq = 1260 - qq; flip = true; }
    float x = sqrtf(1681.0f + 8.0f * (float)qq);
    int mi = (int)((x - 41.0f) * 0.5f);
    if (mi < 0) mi = 0;
    while (((mi + 1) * (mi + 42)) / 2 <= qq) ++mi;
    while ((mi * (mi + 41)) / 2 > qq)       --mi;
    int off = qq - (mi * (mi + 41)) / 2;
    int ni  = off + (HALF - mi);
    if (flip) { mi = 40 - mi; ni = 40 - ni; }
    return mi | (ni << 8) | ((mi + ni - HALF) << 16);
}

static __device__ __forceinline__ float2 e1_of(const float2 (*sE)[2], int d, int c) {
    float2 a  = sE[d & 255][c];
    float2 bb = sE[(d >> 8) & 255][c];
    float2 dd = sE[(d >> 16) & 255][c];
    float2 ab = make_float2(a.x*bb.x - a.y*bb.y, a.x*bb.y + a.y*bb.x);
    return make_float2(ab.x*dd.x + ab.y*dd.y, ab.y*dd.x - ab.x*dd.y);  // a*bb*conj(dd)
}

// feat1 = E1*t1 (real), feat2 = conj(E1)*t2 -> two packed bf16 complex
static __device__ __forceinline__ uint2 feat(float2 E1, float t1, float2 t2) {
    uint2 r;
    r.x = pk2(E1.x * t1, E1.y * t1);
    r.y = pk2(E1.x*t2.x + E1.y*t2.y, E1.x*t2.y - E1.y*t2.x);
    return r;
}

// Output: complex (B, 2, 2T) C-order, re/im interleaved bf16.
// out viewed as uint (4 B = one bf16 complex); plane (b,c) = 2*NTRIP uints.
__global__ __launch_bounds__(256) void so_features(
    const float* __restrict__ E_real, const float* __restrict__ E_imag,
    unsigned int* __restrict__ out)
{
    __shared__ float2 sE[M41][2];
    __shared__ float  sT1[M41];
    __shared__ float2 sT2[M41];
    __shared__ float2 sE1[QSLOTS][2];   // E1(q, c) for the block's q-window
    __shared__ uint4  stA[512];         // plane0 staging: 1024 t * 8 B = 8 KB
    __shared__ uint4  stB[512];         // plane1 staging: 8 KB

    const int b     = blockIdx.y;
    const int tid   = threadIdx.x;
    const int tbase = blockIdx.x << 10;     // 1024 t per block per plane
    const int q_lo  = tbase / M41;

    // Group-covered t in this block: [tbase, tbase + nvalid), nvalid <= 1024.
    const int nvalid = min(1024, (NTRIP - 1) - tbase);   // 1024, or 500 for bx=50
    const int t0 = tbase + 4 * tid;
    char* const oc = (char*)out;
    const size_t plane = 8ull * (size_t)NTRIP;           // 413608 bytes per plane
    const size_t pb0 = (size_t)(2*b)     * plane + 8ull * (size_t)tbase;
    const size_t pb1 = (size_t)(2*b + 1) * plane + 8ull * (size_t)tbase;

    for (int rep = 0; rep < REP; ++rep) {

    if (tid < 2 * M41) {
        int base = b * (2 * M41) + tid;
        sE[tid >> 1][tid & 1] = make_float2(E_real[base], E_imag[base]);
    }
    __syncthreads();

    if (tid < M41) {
        float2 e0 = sE[tid][0], e1 = sE[tid][1];
        sT1[tid] = e0.x*e0.x + e0.y*e0.y + e1.x*e1.x + e1.y*e1.y;
        float2 g0 = sE[40 - tid][0], g1 = sE[40 - tid][1];
        sT2[tid] = make_float2(
            e0.x*g0.x - e0.y*g0.y + e1.x*g1.x - e1.y*g1.y,
            e0.x*g0.y + e0.y*g0.x + e1.x*g1.y + e1.y*g1.x);
    } else if (tid >= 64 && tid < 64 + QSLOTS) {
        int q = q_lo + (tid - 64);
        if (q <= NPAIR - 1) {
            int d = pair_decode(q);
            sE1[tid - 64][0] = e1_of(sE, d, 0);
            sE1[tid - 64][1] = e1_of(sE, d, 1);
        }
    }
    __syncthreads();

    if (4 * tid < nvalid) {
        int q0 = t0 / M41;          // magic-mul div
        int k  = t0 - q0 * M41;
        int dq = q0 - q_lo;         // 0 <= dq <= 25; ++ at most once below -> <= 26
        unsigned int A[8], Bv[8];
        #pragma unroll
        for (int j = 0; j < 4; ++j) {
            float  t1v = sT1[k];
            float2 t2v = sT2[k];
            uint2 fA = feat(sE1[dq][0], t1v, t2v);
            uint2 fB = feat(sE1[dq][1], t1v, t2v);
            A[2*j]  = fA.x;  A[2*j + 1]  = fA.y;
            Bv[2*j] = fB.x;  Bv[2*j + 1] = fB.y;
            if (++k == M41) { k = 0; ++dq; }
        }
        stA[2*tid]     = make_uint4(A[0],  A[1],  A[2],  A[3]);
        stA[2*tid + 1] = make_uint4(A[4],  A[5],  A[6],  A[7]);
        stB[2*tid]     = make_uint4(Bv[0], Bv[1], Bv[2], Bv[3]);
        stB[2*tid + 1] = make_uint4(Bv[4], Bv[5], Bv[6], Bv[7]);
    } else if (t0 == NTRIP - 1) {
        // solo t = 51700 (q = 1260, k = 40), both planes, written directly.
        int dq = (NPAIR - 1) - q_lo;                     // = 12 in block 50
        uint2 vA = feat(sE1[dq][0], sT1[40], sT2[40]);
        uint2 vB = feat(sE1[dq][1], sT1[40], sT2[40]);
        *(uint2*)(oc + (size_t)(2*b)     * plane + 8ull * (size_t)(NTRIP - 1)) = vA;
        *(uint2*)(oc + (size_t)(2*b + 1) * plane + 8ull * (size_t)(NTRIP - 1)) = vB;
    }
    __syncthreads();

    // Lane-dense cooperative stores of the staged slabs.
    const uint2* sB2 = (const uint2*)stB;
    if (nvalid == 1024) {
        *(uint4*)(oc + pb0 +        16u * tid) = stA[tid];
        *(uint4*)(oc + pb0 + 4096 + 16u * tid) = stA[tid + 256];
        *(uint2*)(oc + pb1 +         8u * tid) = sB2[tid];
        *(uint2*)(oc + pb1 + 2048 +  8u * tid) = sB2[tid + 256];
        *(uint2*)(oc + pb1 + 4096 +  8u * tid) = sB2[tid + 512];
        *(uint2*)(oc + pb1 + 6144 +  8u * tid) = sB2[tid + 768];
    } else {
        const int nu4 = nvalid >> 1;                     // 250 for bx=50
        for (int u = tid; u < nu4; u += 256)
            *(uint4*)(oc + pb0 + 16u * (unsigned)u) = stA[u];
        for (int u = tid; u < nvalid; u += 256)          // 500 uint2
            *(uint2*)(oc + pb1 + 8u * (unsigned)u) = sB2[u];
    }
    __syncthreads();   // protect sE/staging rewrite in the next rep

    } // rep
}

extern "C" void kernel_launch(void* const* d_in, const int* in_sizes, int n_in,
                              void* d_out, int out_size, void* d_ws, size_t ws_size,
                              hipStream_t stream) {
    // Verified R6: inputs arrive with d_in[0] = E_imag, d_in[1] = E_real.
    const float* E_imag = (const float*)d_in[0];
    const float* E_real = (const float*)d_in[1];
    unsigned int* out = (unsigned int*)d_out;

    int B = in_sizes[0] / (2 * M41);   // 128 for the bench shapes

    dim3 grid((NTRIP + 1023) / 1024, B);   // 51 x B
    so_features<<<grid, 256, 0, stream>>>(E_real, E_imag, out);
}

// Round 5
// 113.945 us; speedup vs baseline: 1.6018x; 1.6018x over previous
//
#include <hip/hip_runtime.h>
#include <hip/hip_bf16.h>

// Problem constants (M=41 in the reference)
#define M41    41
#define HALF   20
#define NPAIR  1261            // #(m,n) with |m|,|n|<=20 and |m+n|<=20
#define NTRIP  (NPAIR * M41)   // 51701 triplets per plane
#define QSLOTS 28              // max distinct q per 1024-t block window (<=26) + slack

// R11 == R10 resubmit (R4 bench died in container acquisition, not the kernel).
// R10: REP diagnostics done (R8/R9). Findings: no spills (FETCH~365KB), pass
// cost 9.9us (10.7 TB/s effective), fixed in-dispatch cost F~22us = cold-store
// drain colliding with the harness poison-fill's LLC eviction backlog. Kernel
// is write-drain-bound at REP=1; compute trims below are the discriminating
// A/B (expected ~neutral) + conflict hygiene.
//  - staging split lo/hi: ds_write_b128 stride 32B (2x conflicted) -> 16B (clean)
//  - E1 hoisted out of the j-loop (reload only at the <=1 q-boundary)

#if defined(__has_builtin)
# if __has_builtin(__builtin_amdgcn_cvt_pk_bf16_f32)
#  define HAVE_PK_BF16 1
# endif
#endif

static __device__ __forceinline__ unsigned short f2bf_sw(float f) {
    unsigned int u = __float_as_uint(f);
    unsigned int r = u + 0x7fffu + ((u >> 16) & 1u);   // RNE (finite inputs)
    return (unsigned short)(r >> 16);
}
static __device__ __forceinline__ unsigned int pk2(float lo, float hi) {
#ifdef HAVE_PK_BF16
    typedef __bf16 bf2 __attribute__((ext_vector_type(2)));
    union { bf2 v; unsigned int u; } cv;
    cv.v = __builtin_amdgcn_cvt_pk_bf16_f32(lo, hi);   // lo -> low half
    return cv.u;
#else
    return (unsigned int)f2bf_sw(lo) | ((unsigned int)f2bf_sw(hi) << 16);
#endif
}

// q -> packed (mi | ni<<8 | mni<<16).  Closed-form inversion of the Python
// (m,n) enumeration; integer while-loops make it exact for all q.
static __device__ __forceinline__ int pair_decode(int q) {
    int qq = q; bool flip = false;
    if (qq >= 651) { qq = 1260 - qq; flip = true; }
    float x = sqrtf(1681.0f + 8.0f * (float)qq);
    int mi = (int)((x - 41.0f) * 0.5f);
    if (mi < 0) mi = 0;
    while (((mi + 1) * (mi + 42)) / 2 <= qq) ++mi;
    while ((mi * (mi + 41)) / 2 > qq)       --mi;
    int off = qq - (mi * (mi + 41)) / 2;
    int ni  = off + (HALF - mi);
    if (flip) { mi = 40 - mi; ni = 40 - ni; }
    return mi | (ni << 8) | ((mi + ni - HALF) << 16);
}

static __device__ __forceinline__ float2 e1_of(const float2 (*sE)[2], int d, int c) {
    float2 a  = sE[d & 255][c];
    float2 bb = sE[(d >> 8) & 255][c];
    float2 dd = sE[(d >> 16) & 255][c];
    float2 ab = make_float2(a.x*bb.x - a.y*bb.y, a.x*bb.y + a.y*bb.x);
    return make_float2(ab.x*dd.x + ab.y*dd.y, ab.y*dd.x - ab.x*dd.y);  // a*bb*conj(dd)
}

// feat1 = E1*t1 (real), feat2 = conj(E1)*t2 -> two packed bf16 complex
static __device__ __forceinline__ uint2 feat(float2 E1, float t1, float2 t2) {
    uint2 r;
    r.x = pk2(E1.x * t1, E1.y * t1);
    r.y = pk2(E1.x*t2.x + E1.y*t2.y, E1.x*t2.y - E1.y*t2.x);
    return r;
}

// Output: complex (B, 2, 2T) C-order, re/im interleaved bf16.
// out viewed as uint (4 B = one bf16 complex); plane (b,c) = 2*NTRIP uints.
__global__ __launch_bounds__(256) void so_features(
    const float* __restrict__ E_real, const float* __restrict__ E_imag,
    unsigned int* __restrict__ out)
{
    __shared__ float2 sE[M41][2];
    __shared__ float  sT1[M41];
    __shared__ float2 sT2[M41];
    __shared__ float2 sE1[QSLOTS][2];   // E1(q, c) for the block's q-window
    // Staging, split lo/hi so each thread's two uint4 writes are 16B-stride
    // (conflict-free b128); reads become 2-way (free on wave64).
    //   stAlo[v] holds t = 4v..4v+1 ; stAhi[v] holds t = 4v+2..4v+3  (plane 0)
    //   stBlo[v] holds t = 4v..4v+1 ; stBhi[v] holds t = 4v+2..4v+3  (plane 1)
    __shared__ uint4 stAlo[256], stAhi[256];
    __shared__ uint4 stBlo[256], stBhi[256];

    const int b     = blockIdx.y;
    const int tid   = threadIdx.x;
    const int tbase = blockIdx.x << 10;     // 1024 t per block per plane
    const int q_lo  = tbase / M41;

    if (tid < 2 * M41) {
        int base = b * (2 * M41) + tid;
        sE[tid >> 1][tid & 1] = make_float2(E_real[base], E_imag[base]);
    }
    __syncthreads();

    if (tid < M41) {
        float2 e0 = sE[tid][0], e1 = sE[tid][1];
        sT1[tid] = e0.x*e0.x + e0.y*e0.y + e1.x*e1.x + e1.y*e1.y;
        float2 g0 = sE[40 - tid][0], g1 = sE[40 - tid][1];
        sT2[tid] = make_float2(
            e0.x*g0.x - e0.y*g0.y + e1.x*g1.x - e1.y*g1.y,
            e0.x*g0.y + e0.y*g0.x + e1.x*g1.y + e1.y*g1.x);
    } else if (tid >= 64 && tid < 64 + QSLOTS) {
        int q = q_lo + (tid - 64);
        if (q <= NPAIR - 1) {
            int d = pair_decode(q);
            sE1[tid - 64][0] = e1_of(sE, d, 0);
            sE1[tid - 64][1] = e1_of(sE, d, 1);
        }
    }
    __syncthreads();

    // Group-covered t in this block: [tbase, tbase + nvalid), nvalid <= 1024.
    const int nvalid = min(1024, (NTRIP - 1) - tbase);   // 1024, or 500 for bx=50
    const int t0 = tbase + 4 * tid;
    char* const oc = (char*)out;
    const size_t plane = 8ull * (size_t)NTRIP;           // 413608 bytes per plane
    const size_t pb0 = (size_t)(2*b)     * plane + 8ull * (size_t)tbase;
    const size_t pb1 = (size_t)(2*b + 1) * plane + 8ull * (size_t)tbase;

    if (4 * tid < nvalid) {
        int q0 = t0 / M41;          // magic-mul div
        int k  = t0 - q0 * M41;
        int dq = q0 - q_lo;         // 0 <= dq <= 25; ++ at most once below -> <= 26
        float2 E1A = sE1[dq][0];
        float2 E1B = sE1[dq][1];
        unsigned int A[8], Bv[8];
        #pragma unroll
        for (int j = 0; j < 4; ++j) {
            float  t1v = sT1[k];
            float2 t2v = sT2[k];
            uint2 fA = feat(E1A, t1v, t2v);
            uint2 fB = feat(E1B, t1v, t2v);
            A[2*j]  = fA.x;  A[2*j + 1]  = fA.y;
            Bv[2*j] = fB.x;  Bv[2*j + 1] = fB.y;
            if (++k == M41) {       // at most one q-boundary per thread
                k = 0; ++dq;
                E1A = sE1[dq][0];
                E1B = sE1[dq][1];
            }
        }
        stAlo[tid] = make_uint4(A[0],  A[1],  A[2],  A[3]);
        stAhi[tid] = make_uint4(A[4],  A[5],  A[6],  A[7]);
        stBlo[tid] = make_uint4(Bv[0], Bv[1], Bv[2], Bv[3]);
        stBhi[tid] = make_uint4(Bv[4], Bv[5], Bv[6], Bv[7]);
    } else if (t0 == NTRIP - 1) {
        // solo t = 51700 (q = 1260, k = 40), both planes, written directly.
        int dq = (NPAIR - 1) - q_lo;                     // = 12 in block 50
        uint2 vA = feat(sE1[dq][0], sT1[40], sT2[40]);
        uint2 vB = feat(sE1[dq][1], sT1[40], sT2[40]);
        *(uint2*)(oc + (size_t)(2*b)     * plane + 8ull * (size_t)(NTRIP - 1)) = vA;
        *(uint2*)(oc + (size_t)(2*b + 1) * plane + 8ull * (size_t)(NTRIP - 1)) = vB;
    }
    __syncthreads();

    // Lane-dense cooperative stores of the staged slabs.
    // Plane 0: global uint4 g holds t = 2g..2g+1 -> (g&1) ? stAhi[g>>1] : stAlo[g>>1]
    // Plane 1: global uint2 w holds t = w -> v=w>>2, r=w&3:
    //          r<2 -> ((uint2*)stBlo)[2v+r] ; r>=2 -> ((uint2*)stBhi)[2v+(r&1)]
    const int h = tid >> 1;
    const uint4* srcA = (tid & 1) ? stAhi : stAlo;
    const uint2* srcB = (tid & 2) ? (const uint2*)stBhi : (const uint2*)stBlo;
    const int idxB = ((tid >> 2) << 1) | (tid & 1);

    if (nvalid == 1024) {
        *(uint4*)(oc + pb0 +        16u * tid) = srcA[h];
        *(uint4*)(oc + pb0 + 4096 + 16u * tid) = srcA[h + 128];
        *(uint2*)(oc + pb1 +         8u * tid) = srcB[idxB];
        *(uint2*)(oc + pb1 + 2048 +  8u * tid) = srcB[idxB + 128];
        *(uint2*)(oc + pb1 + 4096 +  8u * tid) = srcB[idxB + 256];
        *(uint2*)(oc + pb1 + 6144 +  8u * tid) = srcB[idxB + 384];
    } else {
        // bx=50: 500 valid t -> 250 uint4 (plane0), 500 uint2 (plane1)
        if (tid < 250)
            *(uint4*)(oc + pb0 + 16u * tid) = srcA[h];
        *(uint2*)(oc + pb1 + 8u * tid) = srcB[idxB];         // w = tid < 500
        if (tid < 244)
            *(uint2*)(oc + pb1 + 2048 + 8u * tid) = srcB[idxB + 128];
    }
}

extern "C" void kernel_launch(void* const* d_in, const int* in_sizes, int n_in,
                              void* d_out, int out_size, void* d_ws, size_t ws_size,
                              hipStream_t stream) {
    // Verified R6: inputs arrive with d_in[0] = E_imag, d_in[1] = E_real.
    const float* E_imag = (const float*)d_in[0];
    const float* E_real = (const float*)d_in[1];
    unsigned int* out = (unsigned int*)d_out;

    int B = in_sizes[0] / (2 * M41);   // 128 for the bench shapes

    dim3 grid((NTRIP + 1023) / 1024, B);   // 51 x B
    so_features<<<grid, 256, 0, stream>>>(E_real, E_imag, out);
}